// Round 1
// baseline (286.823 us; speedup 1.0000x reference)
//
#include <hip/hip_runtime.h>
#include <hip/hip_bf16.h>
#include <stdint.h>

#define B_ 32
#define T_ 2048
#define D_ 128
#define BQ 128
#define BK 64

typedef __attribute__((ext_vector_type(8))) __bf16 bf16x8;
typedef __attribute__((ext_vector_type(16))) float f32x16;

__device__ __forceinline__ float fast_exp2(float x) {
#if __has_builtin(__builtin_amdgcn_exp2f)
    return __builtin_amdgcn_exp2f(x);
#else
    return exp2f(x);
#endif
}

__device__ __forceinline__ f32x16 zero16() {
    f32x16 z;
    #pragma unroll
    for (int i = 0; i < 16; ++i) z[i] = 0.f;
    return z;
}

// pack two f32 -> one u32 of 2x bf16 (compiler emits v_cvt_pk_bf16_f32; do NOT hand-asm, m240)
__device__ __forceinline__ uint32_t pk2(float a, float b) {
    union { __hip_bfloat16 h; unsigned short u; } ua, ub;
    ua.h = __float2bfloat16(a); ub.h = __float2bfloat16(b);
    return (uint32_t)ua.u | ((uint32_t)ub.u << 16);
}

// swap lane-halves between two regs: a'[32:63]=b[0:31], b'[0:31]=a[32:63] (gfx950)
__device__ __forceinline__ void plswap(uint32_t& a, uint32_t& b) {
    asm("v_permlane32_swap_b32 %0, %1" : "+v"(a), "+v"(b));
}

// ---------------- prep 1: K fp32 [b][k][d] -> Kb bf16 (same layout) ----------------
__global__ __launch_bounds__(256, 4)
void prep_k(const float* __restrict__ K, const int* __restrict__ vlens,
            __hip_bfloat16* __restrict__ Kb)
{
    const int b = blockIdx.y, k0 = blockIdx.x * 64;
    const int kmax = (vlens[b] + 63) & ~63;        // main kernel never reads past ceil64(vlen)
    if (k0 >= kmax) return;
    const float4* src = (const float4*)(K + ((size_t)b * T_ + k0) * D_);
    uint2* dst = (uint2*)(Kb + ((size_t)b * T_ + k0) * D_);
    #pragma unroll
    for (int it = 0; it < 8; ++it) {
        int c = it * 256 + threadIdx.x;            // 2048 float4 chunks (64 rows x 128 d)
        float4 v = src[c];
        union { __hip_bfloat16 h[4]; uint2 u; } pk;
        pk.h[0] = __float2bfloat16(v.x); pk.h[1] = __float2bfloat16(v.y);
        pk.h[2] = __float2bfloat16(v.z); pk.h[3] = __float2bfloat16(v.w);
        dst[c] = pk.u;
    }
}

// ---------------- prep 2: V fp32 [b][k][d] -> VTb bf16 [b][d][k] ----------------
__global__ __launch_bounds__(256, 2)
void prep_vt(const float* __restrict__ V, const int* __restrict__ vlens,
             __hip_bfloat16* __restrict__ VTb)
{
    __shared__ float tile[64][132];                // 132: float4-aligned rows (528 B)
    const int b = blockIdx.y, k0 = blockIdx.x * 64;
    const int kmax = (vlens[b] + 63) & ~63;
    if (k0 >= kmax) return;
    const float4* src = (const float4*)(V + ((size_t)b * T_ + k0) * D_);
    #pragma unroll
    for (int it = 0; it < 8; ++it) {
        int c = it * 256 + threadIdx.x;
        int row = c >> 5, c4 = c & 31;
        *(float4*)&tile[row][c4 * 4] = src[c];
    }
    __syncthreads();
    #pragma unroll
    for (int it = 0; it < 8; ++it) {
        int c = it * 256 + threadIdx.x;            // 2048 chunks of 4 keys
        int kc = c & 15, d = c >> 4;
        union { __hip_bfloat16 h[4]; uint2 u; } pk;
        #pragma unroll
        for (int j = 0; j < 4; ++j) {
            int jj = (j + kc) & 3;                 // rotate reads to spread LDS banks
            pk.h[jj] = __float2bfloat16(tile[kc * 4 + jj][d]);
        }
        *(uint2*)(VTb + ((size_t)b * D_ + d) * T_ + k0 + kc * 4) = pk.u;
    }
}

// ---------------- main: flash attention, 4 waves x 32 q-rows (BQ=128), 32x32x16 MFMA ----------------
// SWAPPED QK^T: S = mfma(K, Q) -> C[m=key][n=q], col(lane&31)=q, row=key via
// (r&3)+8*(r>>2)+4*hi  [m74/m101 layout]. Each lane then owns P[*][q=lane&31]
// -> softmax + P->bf16 A-frags fully in-register (pk2 + v_permlane32_swap_b32),
// no sP LDS round-trip. Row-sum l is a per-lane VALU accumulation.
// K/V tiles double-buffered in LDS; ONE barrier per k-iter; next tile's global
// loads issued at iter top (latency hides under QK^T+softmax+PV).
__global__ __launch_bounds__(256, 2)
void attn_main(const float* __restrict__ Q, const int* __restrict__ vlens,
               const __hip_bfloat16* __restrict__ Kb,
               const __hip_bfloat16* __restrict__ VTb,
               float* __restrict__ out)
{
    const int tid  = threadIdx.x;
    const int wave = tid >> 6;          // 0..3, owns q-rows [wave*32, wave*32+32)
    const int lane = tid & 63;
    const int l32  = lane & 31;
    const int hi   = lane >> 5;

    const int b    = blockIdx.y;
    const int q0   = blockIdx.x * BQ;
    const int vlen = vlens[b];
    const int nkb  = (vlen + 63) >> 6;

    // padded rows: conflict-free b128 access (measured 0 conflicts with these strides)
    __shared__ __hip_bfloat16 sK [2][64][136];   // K tile  [key][d]   2x17 KiB
    __shared__ __hip_bfloat16 sVT[2][128][72];   // V tile  [d][key]   2x18 KiB

    // ---- Q B-frags: B[k=d][n=q], lane&31 = q, 8 d-steps, kept in registers ----
    bf16x8 qf[8];
    {
        const float* qp = Q + ((size_t)b * T_ + q0 + wave * 32 + l32) * D_ + hi * 8;
        #pragma unroll
        for (int ds = 0; ds < 8; ++ds) {
            const float4* p4 = (const float4*)(qp + ds * 16);
            float4 a = p4[0], c = p4[1];
            __hip_bfloat16 h[8] = {
                __float2bfloat16(a.x), __float2bfloat16(a.y),
                __float2bfloat16(a.z), __float2bfloat16(a.w),
                __float2bfloat16(c.x), __float2bfloat16(c.y),
                __float2bfloat16(c.z), __float2bfloat16(c.w) };
            qf[ds] = *(const bf16x8*)h;
        }
    }

    f32x16 o[4];                         // O[q][d], 4 d-tiles of 32
    #pragma unroll
    for (int dt = 0; dt < 4; ++dt) o[dt] = zero16();
    float lsum = 0.f;                    // per-lane partial row-sum for q = lane&31

    const float C = 1.4426950408889634f / 256.0f;  // log2(e) / (2*d)

    const __hip_bfloat16* kb_base = Kb  + (size_t)b * T_ * D_;
    const __hip_bfloat16* vt_base = VTb + (size_t)b * D_ * T_;

    uint4 kreg[4], vreg[4];              // staging regs (K: 4x16B, V: 4x16B per thread)

    // ---- prologue: stage tile 0 into buffer 0 ----
    if (nkb > 0) {
        #pragma unroll
        for (int it = 0; it < 4; ++it) {
            int c = it * 256 + tid;
            kreg[it] = *(const uint4*)(kb_base + (size_t)(c >> 4) * D_ + (c & 15) * 8);
            vreg[it] = *(const uint4*)(vt_base + (size_t)(c >> 3) * T_ + (c & 7) * 8);
        }
        #pragma unroll
        for (int it = 0; it < 4; ++it) {
            int c = it * 256 + tid;
            *(uint4*)&sK [0][c >> 4][(c & 15) * 8] = kreg[it];
            *(uint4*)&sVT[0][c >> 3][(c & 7)  * 8] = vreg[it];
        }
    }
    __syncthreads();

    int cur = 0;
    for (int kb = 0; kb < nkb; ++kb) {
        const int k0 = kb * 64;
        const bool pfetch = (kb + 1 < nkb);

        // ---- issue next tile's global loads NOW (consumed after PV) ----
        if (pfetch) {
            const __hip_bfloat16* kp = kb_base + (size_t)(k0 + 64) * D_;
            const __hip_bfloat16* vp = vt_base + (k0 + 64);
            #pragma unroll
            for (int it = 0; it < 4; ++it) {
                int c = it * 256 + tid;
                kreg[it] = *(const uint4*)(kp + (size_t)(c >> 4) * D_ + (c & 15) * 8);
                vreg[it] = *(const uint4*)(vp + (size_t)(c >> 3) * T_ + (c & 7) * 8);
            }
        }

        // ---- S = K Q^T (swapped): C[m=key][n=q] ----
        f32x16 s[2];
        s[0] = zero16(); s[1] = zero16();
        __builtin_amdgcn_s_setprio(1);
        #pragma unroll
        for (int ds = 0; ds < 8; ++ds) {
            bf16x8 kf0 = *(const bf16x8*)&sK[cur][l32     ][ds * 16 + hi * 8];
            bf16x8 kf1 = *(const bf16x8*)&sK[cur][32 + l32][ds * 16 + hi * 8];
            s[0] = __builtin_amdgcn_mfma_f32_32x32x16_bf16(kf0, qf[ds], s[0], 0, 0, 0);
            s[1] = __builtin_amdgcn_mfma_f32_32x32x16_bf16(kf1, qf[ds], s[1], 0, 0, 0);
        }
        __builtin_amdgcn_s_setprio(0);

        // ---- softmax (fixed-m, exp2) + in-register P->bf16 A-frag assembly ----
        bf16x8 pf[4];
        #pragma unroll
        for (int nt = 0; nt < 2; ++nt) {
            const int kbase_l = k0 + nt * 32 + 4 * hi;   // lane's key base in this half-tile
            float p[16];
            #pragma unroll
            for (int r = 0; r < 16; ++r) {
                int krow = (r & 3) + 8 * (r >> 2);       // key row offset for reg r
                float e = fast_exp2(s[nt][r] * C);
                p[r] = (kbase_l + krow < vlen) ? e : 0.f;
            }
            // pairwise row-sum (lane's own half of the keys)
            lsum += (((p[0] + p[1]) + (p[2] + p[3])) + ((p[4] + p[5]) + (p[6] + p[7])))
                  + (((p[8] + p[9]) + (p[10] + p[11])) + ((p[12] + p[13]) + (p[14] + p[15])));
            // two 16-key A-frags per half-tile: word j holds keys hi*8 + {2j, 2j+1}
            #pragma unroll
            for (int k2 = 0; k2 < 2; ++k2) {
                const int base = k2 * 8;
                uint32_t A0 = pk2(p[base + 0], p[base + 1]);   // hi0:{0,1}  hi1:{4,5}
                uint32_t B0 = pk2(p[base + 4], p[base + 5]);   // hi0:{8,9}  hi1:{12,13}
                uint32_t A1 = pk2(p[base + 2], p[base + 3]);
                uint32_t B1 = pk2(p[base + 6], p[base + 7]);
                plswap(A0, B0);   // A0: hi0{0,1} hi1{8,9} = word0 ; B0: hi0{4,5} hi1{12,13} = word2
                plswap(A1, B1);   // A1 -> word1 ; B1 -> word3
                union { uint32_t u[4]; bf16x8 v; } fr;
                fr.u[0] = A0; fr.u[1] = A1; fr.u[2] = B0; fr.u[3] = B1;
                pf[nt * 2 + k2] = fr.v;
            }
        }

        // ---- O += P V : 4 k-steps of 16 keys ----
        __builtin_amdgcn_s_setprio(1);
        #pragma unroll
        for (int ks = 0; ks < 4; ++ks)
            #pragma unroll
            for (int dt = 0; dt < 4; ++dt) {
                bf16x8 vf = *(const bf16x8*)&sVT[cur][dt * 32 + l32][ks * 16 + hi * 8];
                o[dt] = __builtin_amdgcn_mfma_f32_32x32x16_bf16(pf[ks], vf, o[dt], 0, 0, 0);
            }
        __builtin_amdgcn_s_setprio(0);

        // ---- write staged regs into the other buffer; ONE barrier per iter ----
        if (pfetch) {
            const int nxt = cur ^ 1;
            #pragma unroll
            for (int it = 0; it < 4; ++it) {
                int c = it * 256 + tid;
                *(uint4*)&sK [nxt][c >> 4][(c & 15) * 8] = kreg[it];
                *(uint4*)&sVT[nxt][c >> 3][(c & 7)  * 8] = vreg[it];
            }
        }
        __syncthreads();
        cur ^= 1;
    }

    // ---- epilogue: full row-sum, O / l ; fully-masked (l==0) -> zeros ----
    lsum += __shfl_xor(lsum, 32);                 // add partner half's keys
    float inv = (lsum > 0.f) ? 1.0f / lsum : 0.f; // lane holds inv for q = lane&31
    float invr[16];
    #pragma unroll
    for (int r = 0; r < 16; ++r)
        invr[r] = __shfl(inv, (r & 3) + 8 * (r >> 2) + 4 * hi);  // inv for this reg's q-row
    #pragma unroll
    for (int dt = 0; dt < 4; ++dt)
        #pragma unroll
        for (int r = 0; r < 16; ++r) {
            int q = (r & 3) + 8 * (r >> 2) + 4 * hi;
            out[((size_t)b * T_ + q0 + wave * 32 + q) * D_ + dt * 32 + l32] = o[dt][r] * invr[r];
        }
}

extern "C" void kernel_launch(void* const* d_in, const int* in_sizes, int n_in,
                              void* d_out, int out_size, void* d_ws, size_t ws_size,
                              hipStream_t stream) {
    const float* Q = (const float*)d_in[0];
    const float* K = (const float*)d_in[1];
    const float* V = (const float*)d_in[2];
    const int* vl  = (const int*)d_in[3];
    float* out     = (float*)d_out;

    // ws: Kb bf16 [B][T][D] (16 MiB) | VTb bf16 [B][D][T] (16 MiB)
    const size_t kb_bytes = (size_t)B_ * T_ * D_ * 2;
    if (ws_size < 2 * kb_bytes) return;   // leaves out zeroed -> absmax 0.3047 signature
    __hip_bfloat16* Kb  = (__hip_bfloat16*)d_ws;
    __hip_bfloat16* VTb = (__hip_bfloat16*)((char*)d_ws + kb_bytes);

    prep_k <<<dim3(T_ / 64, B_), 256, 0, stream>>>(K, vl, Kb);
    prep_vt<<<dim3(T_ / 64, B_), 256, 0, stream>>>(V, vl, VTb);
    attn_main<<<dim3(T_ / BQ, B_), 256, 0, stream>>>(Q, vl, Kb, VTb, out);
}

// Round 2
// 232.718 us; speedup vs baseline: 1.2325x; 1.2325x over previous
//
#include <hip/hip_runtime.h>
#include <hip/hip_bf16.h>
#include <stdint.h>

#define B_ 32
#define T_ 2048
#define D_ 128
#define BQ 128
#define BK 64

typedef __attribute__((ext_vector_type(8))) __bf16 bf16x8;
typedef __attribute__((ext_vector_type(16))) float f32x16;

__device__ __forceinline__ float fast_exp2(float x) {
#if __has_builtin(__builtin_amdgcn_exp2f)
    return __builtin_amdgcn_exp2f(x);
#else
    return exp2f(x);
#endif
}

__device__ __forceinline__ f32x16 zero16() {
    f32x16 z;
    #pragma unroll
    for (int i = 0; i < 16; ++i) z[i] = 0.f;
    return z;
}

// pack two f32 -> one u32 of 2x bf16 (compiler emits v_cvt_pk_bf16_f32; do NOT hand-asm, m240)
__device__ __forceinline__ uint32_t pk2(float a, float b) {
    union { __hip_bfloat16 h; unsigned short u; } ua, ub;
    ua.h = __float2bfloat16(a); ub.h = __float2bfloat16(b);
    return (uint32_t)ua.u | ((uint32_t)ub.u << 16);
}

// swap lane-halves between two regs: a'[32:63]=b[0:31], b'[0:31]=a[32:63] (gfx950)
__device__ __forceinline__ void plswap(uint32_t& a, uint32_t& b) {
    asm("v_permlane32_swap_b32 %0, %1" : "+v"(a), "+v"(b));
}

// async global->LDS, 16B per lane, LDS dest = wave-uniform base + lane*16 (linear)
__device__ __forceinline__ void gll16(const __hip_bfloat16* g, __hip_bfloat16* lds) {
    __builtin_amdgcn_global_load_lds(
        (const __attribute__((address_space(1))) uint32_t*)g,
        (__attribute__((address_space(3))) uint32_t*)lds,
        16, 0, 0);
}

// ---------------- prep 1: K fp32 [b][k][d] -> Kb bf16 (same layout) ----------------
__global__ __launch_bounds__(256, 4)
void prep_k(const float* __restrict__ K, const int* __restrict__ vlens,
            __hip_bfloat16* __restrict__ Kb)
{
    const int b = blockIdx.y, k0 = blockIdx.x * 64;
    const int kmax = (vlens[b] + 63) & ~63;        // main kernel never reads past ceil64(vlen)
    if (k0 >= kmax) return;
    const float4* src = (const float4*)(K + ((size_t)b * T_ + k0) * D_);
    uint2* dst = (uint2*)(Kb + ((size_t)b * T_ + k0) * D_);
    #pragma unroll
    for (int it = 0; it < 8; ++it) {
        int c = it * 256 + threadIdx.x;            // 2048 float4 chunks (64 rows x 128 d)
        float4 v = src[c];
        union { __hip_bfloat16 h[4]; uint2 u; } pk;
        pk.h[0] = __float2bfloat16(v.x); pk.h[1] = __float2bfloat16(v.y);
        pk.h[2] = __float2bfloat16(v.z); pk.h[3] = __float2bfloat16(v.w);
        dst[c] = pk.u;
    }
}

// ---------------- prep 2: V fp32 [b][k][d] -> VTb bf16 [b][d][k] ----------------
__global__ __launch_bounds__(256, 2)
void prep_vt(const float* __restrict__ V, const int* __restrict__ vlens,
             __hip_bfloat16* __restrict__ VTb)
{
    __shared__ float tile[64][132];                // 132: float4-aligned rows (528 B)
    const int b = blockIdx.y, k0 = blockIdx.x * 64;
    const int kmax = (vlens[b] + 63) & ~63;
    if (k0 >= kmax) return;
    const float4* src = (const float4*)(V + ((size_t)b * T_ + k0) * D_);
    #pragma unroll
    for (int it = 0; it < 8; ++it) {
        int c = it * 256 + threadIdx.x;
        int row = c >> 5, c4 = c & 31;
        *(float4*)&tile[row][c4 * 4] = src[c];
    }
    __syncthreads();
    #pragma unroll
    for (int it = 0; it < 8; ++it) {
        int c = it * 256 + threadIdx.x;            // 2048 chunks of 4 keys
        int kc = c & 15, d = c >> 4;
        union { __hip_bfloat16 h[4]; uint2 u; } pk;
        #pragma unroll
        for (int j = 0; j < 4; ++j) {
            int jj = (j + kc) & 3;                 // rotate reads to spread LDS banks
            pk.h[jj] = __float2bfloat16(tile[kc * 4 + jj][d]);
        }
        *(uint2*)(VTb + ((size_t)b * D_ + d) * T_ + k0 + kc * 4) = pk.u;
    }
}

// ---------------- main: flash attention, 4 waves x 32 q-rows (BQ=128), 32x32x16 MFMA ----------------
// SWAPPED QK^T: S = mfma(K, Q) -> C[m=key][n=q], col(lane&31)=q, row=key via
// (r&3)+8*(r>>2)+4*hi  [m74/m101 layout, harness-verified round 1]. Each lane owns
// P[*][q=lane&31] -> softmax + P->bf16 A-frags fully in-register (pk2 + permlane32_swap).
// Staging: global_load_lds (zero staging VGPRs -- round-1's reg-staging spilled:
// WRITE_SIZE 32->164 MB). LDS dest is linear, so bank-conflict fix is the
// both-sides XOR swizzle (rule #21): 16B slot s_phys = s ^ (row&7), applied via the
// per-lane GLOBAL source address on the write side and the same XOR on ds_read side.
// Double-buffered tiles, ONE barrier per k-iter; prefetch issued at iter top.
__global__ __launch_bounds__(256, 2)
void attn_main(const float* __restrict__ Q, const int* __restrict__ vlens,
               const __hip_bfloat16* __restrict__ Kb,
               const __hip_bfloat16* __restrict__ VTb,
               float* __restrict__ out)
{
    const int tid  = threadIdx.x;
    const int wave = tid >> 6;          // 0..3, owns q-rows [wave*32, wave*32+32)
    const int lane = tid & 63;
    const int l32  = lane & 31;
    const int hi   = lane >> 5;

    const int b    = blockIdx.y;
    const int q0   = blockIdx.x * BQ;
    const int vlen = vlens[b];
    const int nkb  = (vlen + 63) >> 6;

    // unpadded (global_load_lds needs linear dest); XOR-swizzled 16B slots instead
    __shared__ __hip_bfloat16 sK [2][64][128];   // K tile  [key][d]   2x16 KiB
    __shared__ __hip_bfloat16 sVT[2][128][64];   // V tile  [d][key]   2x16 KiB

    // ---- Q B-frags: B[k=d][n=q], lane&31 = q, 8 d-steps, kept in registers ----
    bf16x8 qf[8];
    {
        const float* qp = Q + ((size_t)b * T_ + q0 + wave * 32 + l32) * D_ + hi * 8;
        #pragma unroll
        for (int ds = 0; ds < 8; ++ds) {
            const float4* p4 = (const float4*)(qp + ds * 16);
            float4 a = p4[0], c = p4[1];
            __hip_bfloat16 h[8] = {
                __float2bfloat16(a.x), __float2bfloat16(a.y),
                __float2bfloat16(a.z), __float2bfloat16(a.w),
                __float2bfloat16(c.x), __float2bfloat16(c.y),
                __float2bfloat16(c.z), __float2bfloat16(c.w) };
            qf[ds] = *(const bf16x8*)h;
        }
    }

    f32x16 o[4];                         // O[q][d], 4 d-tiles of 32
    #pragma unroll
    for (int dt = 0; dt < 4; ++dt) o[dt] = zero16();
    float lsum = 0.f;                    // per-lane partial row-sum for q = lane&31

    const float C = 1.4426950408889634f / 256.0f;  // log2(e) / (2*d)

    const __hip_bfloat16* kb_base = Kb  + (size_t)b * T_ * D_;
    const __hip_bfloat16* vt_base = VTb + (size_t)b * D_ * T_;

    // ---- stage helpers (wave-cooperative; 4x 1KB DMA each, no VGPR payload) ----
    // K: 1KB block = 4 rows of 256B. lane i -> phys slot (i&15) of row blk*4+(i>>4).
    //    phys slot p holds logical slot p^(row&7)  (s in [0,16), XOR bijective).
    // V: 1KB block = 8 rows of 128B. lane i -> phys slot (i&7) of row blk*8+(i>>3).
    auto stage = [&](int k0s, int buf) {
        #pragma unroll
        for (int it = 0; it < 4; ++it) {
            const int blk = wave * 4 + it;
            {
                const int row = blk * 4 + (lane >> 4);
                const int s   = (lane & 15) ^ (row & 7);
                gll16(kb_base + (size_t)(k0s + row) * D_ + s * 8,
                      &sK[buf][0][0] + blk * 512);
            }
            {
                const int row = blk * 8 + (lane >> 3);   // d-row
                const int s   = (lane & 7) ^ (row & 7);
                gll16(vt_base + (size_t)row * T_ + k0s + s * 8,
                      &sVT[buf][0][0] + blk * 512);
            }
        }
    };

    // ---- prologue: stage tile 0 into buffer 0 ----
    if (nkb > 0) stage(0, 0);
    __syncthreads();                     // implicit vmcnt(0) drains DMA

    int cur = 0;
    for (int kb = 0; kb < nkb; ++kb) {
        const int k0 = kb * 64;

        // ---- issue next tile's DMA NOW; lands during compute, drained at barrier ----
        if (kb + 1 < nkb) stage(k0 + 64, cur ^ 1);

        // ---- S = K Q^T (swapped): C[m=key][n=q]; swizzled K reads ----
        f32x16 s[2];
        s[0] = zero16(); s[1] = zero16();
        __builtin_amdgcn_s_setprio(1);
        #pragma unroll
        for (int ds = 0; ds < 8; ++ds) {
            const int r0 = l32, r1 = 32 + l32;
            bf16x8 kf0 = *(const bf16x8*)&sK[cur][r0][((ds * 2 + hi) ^ (r0 & 7)) * 8];
            bf16x8 kf1 = *(const bf16x8*)&sK[cur][r1][((ds * 2 + hi) ^ (r1 & 7)) * 8];
            s[0] = __builtin_amdgcn_mfma_f32_32x32x16_bf16(kf0, qf[ds], s[0], 0, 0, 0);
            s[1] = __builtin_amdgcn_mfma_f32_32x32x16_bf16(kf1, qf[ds], s[1], 0, 0, 0);
        }
        __builtin_amdgcn_s_setprio(0);

        // ---- softmax (fixed-m, exp2) + in-register P->bf16 A-frag assembly ----
        bf16x8 pf[4];
        #pragma unroll
        for (int nt = 0; nt < 2; ++nt) {
            const int kbase_l = k0 + nt * 32 + 4 * hi;   // lane's key base in this half-tile
            float p[16];
            #pragma unroll
            for (int r = 0; r < 16; ++r) {
                int krow = (r & 3) + 8 * (r >> 2);       // key row offset for reg r
                float e = fast_exp2(s[nt][r] * C);
                p[r] = (kbase_l + krow < vlen) ? e : 0.f;
            }
            // pairwise row-sum (lane's own half of the keys)
            lsum += (((p[0] + p[1]) + (p[2] + p[3])) + ((p[4] + p[5]) + (p[6] + p[7])))
                  + (((p[8] + p[9]) + (p[10] + p[11])) + ((p[12] + p[13]) + (p[14] + p[15])));
            // two 16-key A-frags per half-tile: word j holds keys hi*8 + {2j, 2j+1}
            #pragma unroll
            for (int k2 = 0; k2 < 2; ++k2) {
                const int base = k2 * 8;
                uint32_t A0 = pk2(p[base + 0], p[base + 1]);   // hi0:{0,1}  hi1:{4,5}
                uint32_t B0 = pk2(p[base + 4], p[base + 5]);   // hi0:{8,9}  hi1:{12,13}
                uint32_t A1 = pk2(p[base + 2], p[base + 3]);
                uint32_t B1 = pk2(p[base + 6], p[base + 7]);
                plswap(A0, B0);   // A0: hi0{0,1} hi1{8,9} = word0 ; B0: hi0{4,5} hi1{12,13} = word2
                plswap(A1, B1);   // A1 -> word1 ; B1 -> word3
                union { uint32_t u[4]; bf16x8 v; } fr;
                fr.u[0] = A0; fr.u[1] = A1; fr.u[2] = B0; fr.u[3] = B1;
                pf[nt * 2 + k2] = fr.v;
            }
        }

        // ---- O += P V : 4 k-steps of 16 keys; swizzled V reads ----
        __builtin_amdgcn_s_setprio(1);
        #pragma unroll
        for (int ks = 0; ks < 4; ++ks)
            #pragma unroll
            for (int dt = 0; dt < 4; ++dt) {
                const int r = dt * 32 + l32;
                bf16x8 vf = *(const bf16x8*)&sVT[cur][r][((ks * 2 + hi) ^ (r & 7)) * 8];
                o[dt] = __builtin_amdgcn_mfma_f32_32x32x16_bf16(pf[ks], vf, o[dt], 0, 0, 0);
            }
        __builtin_amdgcn_s_setprio(0);

        // ONE barrier per iter: waits own DMA (vmcnt) + all waves done reading cur
        __syncthreads();
        cur ^= 1;
    }

    // ---- epilogue: full row-sum, O / l ; fully-masked (l==0) -> zeros ----
    lsum += __shfl_xor(lsum, 32);                 // add partner half's keys
    float inv = (lsum > 0.f) ? 1.0f / lsum : 0.f; // lane holds inv for q = lane&31
    float invr[16];
    #pragma unroll
    for (int r = 0; r < 16; ++r)
        invr[r] = __shfl(inv, (r & 3) + 8 * (r >> 2) + 4 * hi);  // inv for this reg's q-row
    #pragma unroll
    for (int dt = 0; dt < 4; ++dt)
        #pragma unroll
        for (int r = 0; r < 16; ++r) {
            int q = (r & 3) + 8 * (r >> 2) + 4 * hi;
            out[((size_t)b * T_ + q0 + wave * 32 + q) * D_ + dt * 32 + l32] = o[dt][r] * invr[r];
        }
}

extern "C" void kernel_launch(void* const* d_in, const int* in_sizes, int n_in,
                              void* d_out, int out_size, void* d_ws, size_t ws_size,
                              hipStream_t stream) {
    const float* Q = (const float*)d_in[0];
    const float* K = (const float*)d_in[1];
    const float* V = (const float*)d_in[2];
    const int* vl  = (const int*)d_in[3];
    float* out     = (float*)d_out;

    // ws: Kb bf16 [B][T][D] (16 MiB) | VTb bf16 [B][D][T] (16 MiB)
    const size_t kb_bytes = (size_t)B_ * T_ * D_ * 2;
    if (ws_size < 2 * kb_bytes) return;   // leaves out zeroed -> absmax 0.3047 signature
    __hip_bfloat16* Kb  = (__hip_bfloat16*)d_ws;
    __hip_bfloat16* VTb = (__hip_bfloat16*)((char*)d_ws + kb_bytes);

    prep_k <<<dim3(T_ / 64, B_), 256, 0, stream>>>(K, vl, Kb);
    prep_vt<<<dim3(T_ / 64, B_), 256, 0, stream>>>(V, vl, VTb);
    attn_main<<<dim3(T_ / BQ, B_), 256, 0, stream>>>(Q, vl, Kb, VTb, out);
}